// Round 4
// baseline (340.619 us; speedup 1.0000x reference)
//
#include <hip/hip_runtime.h>
#include <hip/hip_fp16.h>

// graph_56006373539875: per-edge spring-force scatter.
// R1: global atomics write-through -> 1881us (20G atomics/s wall).
// R2: LDS-privatized 8-range redundant scan -> 240us.
// R3: de-gathered scan -> scatter only 255->238us => scan structure itself
//     (8x redundancy + exec-masked divergent ds_adds) is the wall.
// R4: exact bucketing (counting sort by node range): histogram -> prefix ->
//     emit (id,3xfp16 force) 8B entries -> dense consume (full-lane ds_adds)
//     -> reduce. No redundancy, no divergence, ~320MB total HBM traffic.

#define NRANGE 8
#define NBLD   256      // build blocks (K1/K3 share the same edge chunking)
#define NSLICE 31       // consume slices per range (31 keeps ws under 140.8MB)
#define K1T    256
#define K3T    1024
#define K4T    1024
#define BLOCK  1024     // fallback kernels

struct __attribute__((packed, aligned(4))) F3 { float x, y, z; };

// r = node / range via magic multiply: magic = ceil(2^32/range).
// Valid for node < 2^32 / (magic*range - 2^32); for range=12500 that is
// ~557K >> n_points=100K.

// ---------------- K1: per-(block,range) endpoint histogram ----------------
__global__ __launch_bounds__(K1T) void count_kernel(
    const int* __restrict__ ea, const int* __restrict__ eb,
    unsigned* __restrict__ blockcounts,   // [NBLD][NRANGE]
    int n_edges, unsigned magic)
{
    __shared__ unsigned red[K1T][NRANGE];
    const int b = blockIdx.x;
    const int chunk = (n_edges + NBLD - 1) / NBLD;
    const int e0 = b * chunk, e1 = min(n_edges, e0 + chunk);

    unsigned c[NRANGE];
#pragma unroll
    for (int j = 0; j < NRANGE; ++j) c[j] = 0;

    for (int e = e0 + (int)threadIdx.x; e < e1; e += K1T) {
        unsigned ra = __umulhi((unsigned)ea[e], magic);
        unsigned rb = __umulhi((unsigned)eb[e], magic);
#pragma unroll
        for (int j = 0; j < NRANGE; ++j)
            c[j] += (ra == (unsigned)j) + (rb == (unsigned)j);
    }
#pragma unroll
    for (int j = 0; j < NRANGE; ++j) red[threadIdx.x][j] = c[j];
    __syncthreads();
    for (int s = K1T / 2; s > 0; s >>= 1) {
        if ((int)threadIdx.x < s)
#pragma unroll
            for (int j = 0; j < NRANGE; ++j)
                red[threadIdx.x][j] += red[threadIdx.x + s][j];
        __syncthreads();
    }
    if (threadIdx.x < NRANGE) blockcounts[b * NRANGE + threadIdx.x] = red[0][threadIdx.x];
}

// ---------------- K2: exact prefix over blocks, per range ----------------
__global__ void scan_kernel(const unsigned* __restrict__ blockcounts,
                            unsigned* __restrict__ blockprefix,
                            unsigned* __restrict__ rangetotals)
{
    int r = threadIdx.x;
    if (r < NRANGE) {
        unsigned run = 0;
        for (int b = 0; b < NBLD; ++b) {
            blockprefix[b * NRANGE + r] = run;
            run += blockcounts[b * NRANGE + r];
        }
        rangetotals[r] = run;
    }
}

// ---------------- K3: compute force once, emit packed entries ----------------
__global__ __launch_bounds__(K3T) void emit_kernel(
    const float* __restrict__ points, const float* __restrict__ force,
    const int* __restrict__ ea, const int* __restrict__ eb,
    const unsigned* __restrict__ blockprefix, const unsigned* __restrict__ rangetotals,
    uint2* __restrict__ entries, int n_edges, int range, unsigned magic)
{
    __shared__ unsigned cnt[NRANGE];
    if (threadIdx.x < NRANGE) {
        unsigned base = 0;
        for (unsigned j = 0; j < threadIdx.x; ++j) base += rangetotals[j];
        cnt[threadIdx.x] = base + blockprefix[blockIdx.x * NRANGE + threadIdx.x];
    }
    __syncthreads();

    const F3* __restrict__ P = (const F3*)points;
    const int chunk = (n_edges + NBLD - 1) / NBLD;
    const int e0 = blockIdx.x * chunk, e1 = min(n_edges, e0 + chunk);

    for (int e = e0 + (int)threadIdx.x; e < e1; e += K3T) {
        int a = ea[e], b = eb[e];
        F3 pa = P[a];
        F3 pb = P[b];
        float vx = pb.x - pa.x, vy = pb.y - pa.y, vz = pb.z - pa.z;
        float s = -force[e] * rsqrtf(vx * vx + vy * vy + vz * vz);
        float fx = s * vx, fy = s * vy, fz = s * vz;

        unsigned ra = __umulhi((unsigned)a, magic);
        unsigned rb = __umulhi((unsigned)b, magic);
        unsigned ida = (unsigned)a - ra * (unsigned)range;
        unsigned idb = (unsigned)b - rb * (unsigned)range;

        unsigned hx = __half_as_ushort(__float2half(fx));
        unsigned hy = __half_as_ushort(__float2half(fy));
        unsigned hz = __half_as_ushort(__float2half(fz));
        unsigned nx = __half_as_ushort(__float2half(-fx));
        unsigned ny = __half_as_ushort(__float2half(-fy));
        unsigned nz = __half_as_ushort(__float2half(-fz));

        unsigned slot_a = atomicAdd(&cnt[ra], 1u);
        entries[slot_a] = make_uint2(ida | (hx << 16), hy | (hz << 16));
        unsigned slot_b = atomicAdd(&cnt[rb], 1u);
        entries[slot_b] = make_uint2(idb | (nx << 16), ny | (nz << 16));
    }
}

// ---------------- K4: dense consume, full-lane LDS accumulate ----------------
__global__ __launch_bounds__(K4T) void consume_kernel(
    const uint2* __restrict__ entries, const unsigned* __restrict__ rangetotals,
    float* __restrict__ partial,        // [NSLICE][n_points*3]
    int n_points, int range)
{
    extern __shared__ float lds[];      // range*3
    const int r = blockIdx.x % NRANGE;
    const int slice = blockIdx.x / NRANGE;

    unsigned base = 0;
    for (int j = 0; j < r; ++j) base += rangetotals[j];
    const unsigned cnt = rangetotals[r];
    const unsigned lo = base + (unsigned)((unsigned long long)cnt * slice / NSLICE);
    const unsigned hi = base + (unsigned)((unsigned long long)cnt * (slice + 1) / NSLICE);

    const int nwords = range * 3;
    for (int w = threadIdx.x; w < nwords; w += K4T) lds[w] = 0.0f;
    __syncthreads();

    for (unsigned i = lo + threadIdx.x; i < hi; i += K4T) {
        uint2 q = entries[i];
        unsigned id = q.x & 0xffffu;
        float fx = __half2float(__ushort_as_half((unsigned short)(q.x >> 16)));
        float fy = __half2float(__ushort_as_half((unsigned short)(q.y & 0xffffu)));
        float fz = __half2float(__ushort_as_half((unsigned short)(q.y >> 16)));
        atomicAdd(&lds[id * 3 + 0], fx);
        atomicAdd(&lds[id * 3 + 1], fy);
        atomicAdd(&lds[id * 3 + 2], fz);
    }
    __syncthreads();

    const int total = n_points * 3;
    const int basew = r * range * 3;
    float* dst = partial + (size_t)slice * (size_t)total + basew;
    for (int w = threadIdx.x; w < nwords; w += K4T)
        if (basew + w < total) dst[w] = lds[w];
}

// ---------------- K5: reduce partials + external forces ----------------
__global__ void reduce_kernel(const float* __restrict__ ext,
                              const float* __restrict__ partial,
                              float* __restrict__ out, int n, int nslice)
{
    int i = blockIdx.x * blockDim.x + threadIdx.x;
    if (i >= n) return;
    float s = ext[i];
    for (int c = 0; c < nslice; ++c) s += partial[(size_t)c * (size_t)n + i];
    out[i] = s;
}

// ---------------- fallback: R2 fused redundant scan ----------------
#define NB_FB 32
__global__ __launch_bounds__(BLOCK) void edge_scan_kernel(
    const float* __restrict__ points, const float* __restrict__ force,
    const int* __restrict__ ea, const int* __restrict__ eb,
    float* __restrict__ partial, float* __restrict__ out,
    int n_edges, int n_points, int range, int atomic_mode)
{
    extern __shared__ float lds[];
    const int r = blockIdx.x / NB_FB;
    const int c = blockIdx.x % NB_FB;
    const int node0 = r * range;
    const int nwords = range * 3;
    for (int w = threadIdx.x; w < nwords; w += BLOCK) lds[w] = 0.0f;
    __syncthreads();
    const int chunk = (n_edges + NB_FB - 1) / NB_FB;
    const int e0 = c * chunk, e1 = min(n_edges, e0 + chunk);
    for (int e = e0 + (int)threadIdx.x; e < e1; e += BLOCK) {
        int a = ea[e], b = eb[e];
        int la = a - node0, lb = b - node0;
        bool ha = (unsigned)la < (unsigned)range;
        bool hb = (unsigned)lb < (unsigned)range;
        if (!(ha || hb)) continue;
        float ax = points[3*a], ay = points[3*a+1], az = points[3*a+2];
        float bx = points[3*b], by = points[3*b+1], bz = points[3*b+2];
        float vx = bx-ax, vy = by-ay, vz = bz-az;
        float s = -force[e] * rsqrtf(vx*vx+vy*vy+vz*vz);
        float fx = s*vx, fy = s*vy, fz = s*vz;
        if (ha) { atomicAdd(&lds[la*3+0], fx); atomicAdd(&lds[la*3+1], fy); atomicAdd(&lds[la*3+2], fz); }
        if (hb) { atomicAdd(&lds[lb*3+0], -fx); atomicAdd(&lds[lb*3+1], -fy); atomicAdd(&lds[lb*3+2], -fz); }
    }
    __syncthreads();
    const int basew = node0 * 3;
    const int total = n_points * 3;
    if (atomic_mode) {
        for (int w = threadIdx.x; w < nwords; w += BLOCK)
            if (basew + w < total) atomicAdd(&out[basew + w], lds[w]);
    } else {
        float* dst = partial + (size_t)c * (size_t)total + basew;
        for (int w = threadIdx.x; w < nwords; w += BLOCK)
            if (basew + w < total) dst[w] = lds[w];
    }
}

extern "C" void kernel_launch(void* const* d_in, const int* in_sizes, int n_in,
                              void* d_out, int out_size, void* d_ws, size_t ws_size,
                              hipStream_t stream) {
    const float* points = (const float*)d_in[0];
    const float* ext_f  = (const float*)d_in[1];
    const float* force  = (const float*)d_in[2];
    const int*   ea     = (const int*)d_in[3];
    const int*   eb     = (const int*)d_in[4];
    float* out = (float*)d_out;
    char*  ws  = (char*)d_ws;

    const int n_edges  = in_sizes[2];
    const int total    = out_size;                   // n_points*3
    const int n_points = total / 3;
    const int range    = (n_points + NRANGE - 1) / NRANGE;     // 12500
    const unsigned magic = (unsigned)((0x100000000ULL + range - 1) / (unsigned)range);
    const size_t lds_bytes = (size_t)range * 3 * sizeof(float); // 150000

    const size_t entries_b  = (size_t)2 * n_edges * sizeof(uint2);          // 102.4MB
    const size_t partial_b  = (size_t)NSLICE * total * sizeof(float);       // 37.2MB
    const size_t bcnt_b     = (size_t)NBLD * NRANGE * sizeof(unsigned);     // 8KB
    const size_t need_new   = entries_b + partial_b + 2 * bcnt_b + 64;
    const size_t need_fb    = (size_t)NB_FB * total * sizeof(float);        // 38.4MB

    hipFuncSetAttribute((const void*)consume_kernel,
                        hipFuncAttributeMaxDynamicSharedMemorySize, (int)lds_bytes);
    hipFuncSetAttribute((const void*)edge_scan_kernel,
                        hipFuncAttributeMaxDynamicSharedMemorySize, (int)lds_bytes);

    const int rb = 256;

    if (range <= 0xFFFF && ws_size >= need_new) {
        uint2*    entries     = (uint2*)ws;
        float*    partial     = (float*)(ws + entries_b);
        unsigned* blockcounts = (unsigned*)(ws + entries_b + partial_b);
        unsigned* blockprefix = blockcounts + NBLD * NRANGE;
        unsigned* rangetotals = blockprefix + NBLD * NRANGE;

        count_kernel<<<NBLD, K1T, 0, stream>>>(ea, eb, blockcounts, n_edges, magic);
        scan_kernel<<<1, 64, 0, stream>>>(blockcounts, blockprefix, rangetotals);
        emit_kernel<<<NBLD, K3T, 0, stream>>>(points, force, ea, eb,
                                              blockprefix, rangetotals, entries,
                                              n_edges, range, magic);
        consume_kernel<<<NRANGE * NSLICE, K4T, lds_bytes, stream>>>(
            entries, rangetotals, partial, n_points, range);
        reduce_kernel<<<(total + rb - 1) / rb, rb, 0, stream>>>(
            ext_f, partial, out, total, NSLICE);
    } else if (ws_size >= need_fb) {
        float* partial = (float*)ws;
        edge_scan_kernel<<<NRANGE * NB_FB, BLOCK, lds_bytes, stream>>>(
            points, force, ea, eb, partial, out, n_edges, n_points, range, 0);
        reduce_kernel<<<(total + rb - 1) / rb, rb, 0, stream>>>(
            ext_f, partial, out, total, NB_FB);
    } else {
        hipMemcpyAsync(d_out, (const void*)ext_f, (size_t)total * sizeof(float),
                       hipMemcpyDeviceToDevice, stream);
        edge_scan_kernel<<<NRANGE * NB_FB, BLOCK, lds_bytes, stream>>>(
            points, force, ea, eb, nullptr, out, n_edges, n_points, range, 1);
    }
}

// Round 5
// 165.182 us; speedup vs baseline: 2.0621x; 2.0621x over previous
//
#include <hip/hip_runtime.h>

// graph_56006373539875: per-edge spring-force scatter.
// R1: global f32 atomics -> 1881us (write-through, 20G atomics/s).
// R2: LDS-privatized redundant scan -> 240us.
// R3: de-gathered scan -> scatter 238us (not gather-bound).
// R4: exact bucketing -> 340us; consume 208us. Cross-round invariance:
//     38.4M LDS-atomic lane-ops == 210-255us everywhere => ds_add_f32
//     costs ~3.3 cyc/active-lane/CU. Atomic COUNT is the only knob.
// R5: (a) pack 3 quantized i16 comps into ONE i64 (fields at bits 0/21/42,
//     multi-precision sext-peel decode) -> 1 ds_add_u64 per endpoint =
//     12.8M lane-ops (3x fewer). (b) emit slots via per-wave count/scan/
//     ballot-prefix -> ZERO atomics in build. Integer accum = deterministic.

#define NRANGE 8
#define NBLD   256
#define K1T    1024
#define K3T    1024
#define K4T    1024
#define NSLICE 31
#define WPB    (K3T / 64)        // 16 waves per build block
#define NWAVE  (NBLD * WPB)      // 4096 build waves
#define QSCALE 4096.0f           // fixed-point scale 2^12

struct __attribute__((packed, aligned(4))) F3 { float x, y, z; };

// ---------------- K1: per-WAVE per-range endpoint counts (no atomics) -----
__global__ __launch_bounds__(K1T) void count_kernel(
    const int* __restrict__ ea, const int* __restrict__ eb,
    unsigned* __restrict__ counts,           // [NRANGE][NWAVE]
    int n_edges, int chunk, unsigned magic)
{
    const int wid  = blockIdx.x * WPB + ((int)threadIdx.x >> 6);
    const int lane = (int)threadIdx.x & 63;
    const int e0 = wid * chunk;
    const int e1 = min(n_edges, e0 + chunk);

    unsigned c[NRANGE];
#pragma unroll
    for (int j = 0; j < NRANGE; ++j) c[j] = 0;

    for (int e = e0 + lane; e < e1; e += 64) {
        unsigned ra = __umulhi((unsigned)ea[e], magic);
        unsigned rb = __umulhi((unsigned)eb[e], magic);
#pragma unroll
        for (int j = 0; j < NRANGE; ++j)
            c[j] += (ra == (unsigned)j) + (rb == (unsigned)j);
    }
#pragma unroll
    for (int j = 0; j < NRANGE; ++j) {
        unsigned v = c[j];
#pragma unroll
        for (int off = 32; off > 0; off >>= 1) v += __shfl_down(v, off);
        if (lane == 0) counts[j * NWAVE + wid] = v;
    }
}

// ---------------- K2: exclusive prefix over waves, per range (shfl scan) --
__global__ __launch_bounds__(512) void scan_kernel(
    const unsigned* __restrict__ counts,     // [NRANGE][NWAVE]
    unsigned* __restrict__ waveprefix,       // [NRANGE][NWAVE], range-local
    unsigned* __restrict__ rangetotals)      // [NRANGE]
{
    const int j    = (int)threadIdx.x >> 6;  // wave -> range
    const int lane = (int)threadIdx.x & 63;
    unsigned running = 0;
    for (int c = 0; c < NWAVE / 64; ++c) {
        const int idx = c * 64 + lane;
        unsigned v = counts[j * NWAVE + idx];
        const unsigned orig = v;
#pragma unroll
        for (int off = 1; off < 64; off <<= 1) {
            unsigned t = __shfl_up(v, off);
            if (lane >= off) v += t;
        }
        waveprefix[j * NWAVE + idx] = running + v - orig;   // exclusive
        running += __shfl(v, 63);
    }
    if (lane == 0) rangetotals[j] = running;
}

// ---------------- K3: force once, quantize, ballot-prefix slot, emit ------
__global__ __launch_bounds__(K3T) void emit_kernel(
    const float* __restrict__ points, const float* __restrict__ force,
    const int* __restrict__ ea, const int* __restrict__ eb,
    const unsigned* __restrict__ waveprefix, const unsigned* __restrict__ rangetotals,
    ushort4* __restrict__ entries,           // [2*n_edges] {id, qx, qy, qz}
    int n_edges, int chunk, int range, unsigned magic)
{
    const int wid  = blockIdx.x * WPB + ((int)threadIdx.x >> 6);
    const int lane = (int)threadIdx.x & 63;
    const unsigned long long ltmask = (1ULL << lane) - 1ULL;

    unsigned base[NRANGE];
    unsigned run = 0;
#pragma unroll
    for (int j = 0; j < NRANGE; ++j) {
        base[j] = run + waveprefix[j * NWAVE + wid];
        run += rangetotals[j];
    }

    const F3* __restrict__ P = (const F3*)points;
    const int e0 = wid * chunk;
    const int e1 = min(n_edges, e0 + chunk);

    for (int eBase = e0; eBase < e1; eBase += 64) {
        const int e = eBase + lane;
        const bool valid = e < e1;
        int a = 0, b = 0;
        float f = 0.0f;
        if (valid) { a = ea[e]; b = eb[e]; f = force[e]; }

        F3 pa = P[a];
        F3 pb = P[b];
        float vx = pb.x - pa.x, vy = pb.y - pa.y, vz = pb.z - pa.z;
        float s = -f * rsqrtf(vx * vx + vy * vy + vz * vz + (valid ? 0.0f : 1.0f));

        int qx = __float2int_rn(s * vx * QSCALE);
        int qy = __float2int_rn(s * vy * QSCALE);
        int qz = __float2int_rn(s * vz * QSCALE);
        qx = max(-32767, min(32767, qx));
        qy = max(-32767, min(32767, qy));
        qz = max(-32767, min(32767, qz));

        const unsigned ra  = valid ? __umulhi((unsigned)a, magic) : 0xFFu;
        const unsigned rb2 = valid ? __umulhi((unsigned)b, magic) : 0xFFu;
        const unsigned ida = (unsigned)a - ra  * (unsigned)range;
        const unsigned idb = (unsigned)b - rb2 * (unsigned)range;

        ushort4 entA, entB;
        entA.x = (unsigned short)ida;
        entA.y = (unsigned short)(short)qx;
        entA.z = (unsigned short)(short)qy;
        entA.w = (unsigned short)(short)qz;
        entB.x = (unsigned short)idb;
        entB.y = (unsigned short)(short)(-qx);
        entB.z = (unsigned short)(short)(-qy);
        entB.w = (unsigned short)(short)(-qz);

#pragma unroll
        for (int j = 0; j < NRANGE; ++j) {
            unsigned long long mA = __ballot(ra == (unsigned)j);
            if (ra == (unsigned)j)
                entries[base[j] + __popcll(mA & ltmask)] = entA;
            base[j] += (unsigned)__popcll(mA);
            unsigned long long mB = __ballot(rb2 == (unsigned)j);
            if (rb2 == (unsigned)j)
                entries[base[j] + __popcll(mB & ltmask)] = entB;
            base[j] += (unsigned)__popcll(mB);
        }
    }
}

// ---------------- K4: dense consume, ONE ds_add_u64 per entry -------------
__global__ __launch_bounds__(K4T) void consume_kernel(
    const ushort4* __restrict__ entries, const unsigned* __restrict__ rangetotals,
    float* __restrict__ partial,             // [NSLICE][n_points*3]
    int n_points, int range)
{
    extern __shared__ unsigned long long lds64[];   // [range]
    const int r     = blockIdx.x % NRANGE;
    const int slice = blockIdx.x / NRANGE;

    unsigned base = 0;
    for (int j = 0; j < r; ++j) base += rangetotals[j];
    const unsigned cnt = rangetotals[r];
    const unsigned lo = base + (unsigned)((unsigned long long)cnt * slice / NSLICE);
    const unsigned hi = base + (unsigned)((unsigned long long)cnt * (slice + 1) / NSLICE);

    for (int w = threadIdx.x; w < range; w += K4T) lds64[w] = 0ULL;
    __syncthreads();

    for (unsigned i = lo + threadIdx.x; i < hi; i += K4T) {
        ushort4 q = entries[i];
        long long v = (long long)(short)q.y
                    + ((long long)(short)q.z << 21)
                    + ((long long)(short)q.w << 42);
        atomicAdd(&lds64[q.x], (unsigned long long)v);
    }
    __syncthreads();

    const int total = n_points * 3;
    const int basew = r * range * 3;
    const float inv = 1.0f / QSCALE;
    for (int w = threadIdx.x; w < range; w += K4T) {
        if (r * range + w >= n_points) continue;
        long long T = (long long)lds64[w];
        long long X = ((long long)((unsigned long long)T << 43)) >> 43;
        T = (T - X) >> 21;
        long long Y = ((long long)((unsigned long long)T << 43)) >> 43;
        T = (T - Y) >> 21;
        long long Z = ((long long)((unsigned long long)T << 42)) >> 42;
        float* dst = partial + (size_t)slice * (size_t)total + basew + 3 * w;
        dst[0] = (float)X * inv;
        dst[1] = (float)Y * inv;
        dst[2] = (float)Z * inv;
    }
}

// ---------------- K5: reduce partials + external forces -------------------
__global__ void reduce_kernel(const float* __restrict__ ext,
                              const float* __restrict__ partial,
                              float* __restrict__ out, int n, int nslice)
{
    int i = blockIdx.x * blockDim.x + threadIdx.x;
    if (i >= n) return;
    float s = ext[i];
    for (int c = 0; c < nslice; ++c) s += partial[(size_t)c * (size_t)n + i];
    out[i] = s;
}

// ---------------- fallback: R2 fused redundant scan -----------------------
#define NB_FB 32
#define BLOCK 1024
__global__ __launch_bounds__(BLOCK) void edge_scan_kernel(
    const float* __restrict__ points, const float* __restrict__ force,
    const int* __restrict__ ea, const int* __restrict__ eb,
    float* __restrict__ partial, float* __restrict__ out,
    int n_edges, int n_points, int range, int atomic_mode)
{
    extern __shared__ float lds[];
    const int r = blockIdx.x / NB_FB;
    const int c = blockIdx.x % NB_FB;
    const int node0 = r * range;
    const int nwords = range * 3;
    for (int w = threadIdx.x; w < nwords; w += BLOCK) lds[w] = 0.0f;
    __syncthreads();
    const int chunk = (n_edges + NB_FB - 1) / NB_FB;
    const int e0 = c * chunk, e1 = min(n_edges, e0 + chunk);
    for (int e = e0 + (int)threadIdx.x; e < e1; e += BLOCK) {
        int a = ea[e], b = eb[e];
        int la = a - node0, lb = b - node0;
        bool ha = (unsigned)la < (unsigned)range;
        bool hb = (unsigned)lb < (unsigned)range;
        if (!(ha || hb)) continue;
        float ax = points[3*a], ay = points[3*a+1], az = points[3*a+2];
        float bx = points[3*b], by = points[3*b+1], bz = points[3*b+2];
        float vx = bx-ax, vy = by-ay, vz = bz-az;
        float s = -force[e] * rsqrtf(vx*vx+vy*vy+vz*vz);
        float fx = s*vx, fy = s*vy, fz = s*vz;
        if (ha) { atomicAdd(&lds[la*3+0], fx); atomicAdd(&lds[la*3+1], fy); atomicAdd(&lds[la*3+2], fz); }
        if (hb) { atomicAdd(&lds[lb*3+0], -fx); atomicAdd(&lds[lb*3+1], -fy); atomicAdd(&lds[lb*3+2], -fz); }
    }
    __syncthreads();
    const int basew = node0 * 3;
    const int total = n_points * 3;
    if (atomic_mode) {
        for (int w = threadIdx.x; w < nwords; w += BLOCK)
            if (basew + w < total) atomicAdd(&out[basew + w], lds[w]);
    } else {
        float* dst = partial + (size_t)c * (size_t)total + basew;
        for (int w = threadIdx.x; w < nwords; w += BLOCK)
            if (basew + w < total) dst[w] = lds[w];
    }
}

extern "C" void kernel_launch(void* const* d_in, const int* in_sizes, int n_in,
                              void* d_out, int out_size, void* d_ws, size_t ws_size,
                              hipStream_t stream) {
    const float* points = (const float*)d_in[0];
    const float* ext_f  = (const float*)d_in[1];
    const float* force  = (const float*)d_in[2];
    const int*   ea     = (const int*)d_in[3];
    const int*   eb     = (const int*)d_in[4];
    float* out = (float*)d_out;
    char*  ws  = (char*)d_ws;

    const int n_edges  = in_sizes[2];
    const int total    = out_size;                       // n_points*3
    const int n_points = total / 3;
    const int range    = (n_points + NRANGE - 1) / NRANGE;   // 12500
    const unsigned magic = (unsigned)((0x100000000ULL + range - 1) / (unsigned)range);
    const int chunk = (n_edges + NWAVE - 1) / NWAVE;

    const size_t lds_consume = (size_t)range * sizeof(unsigned long long); // 100KB
    const size_t lds_fb      = (size_t)range * 3 * sizeof(float);          // 150KB

    const size_t entries_b = (size_t)2 * n_edges * sizeof(ushort4);        // 102.4MB
    const size_t partial_b = (size_t)NSLICE * total * sizeof(float);       // 37.2MB
    const size_t cnt_b     = (size_t)NRANGE * NWAVE * sizeof(unsigned);    // 128KB
    // counters alias the partial region (disjoint lifetimes: K1-K3 vs K4-K5)
    const size_t tail_need = (2 * cnt_b + 64 > partial_b) ? (2 * cnt_b + 64) : partial_b;
    const size_t need_new  = entries_b + tail_need;
    const size_t need_fb   = (size_t)NB_FB * total * sizeof(float);        // 38.4MB

    hipFuncSetAttribute((const void*)consume_kernel,
                        hipFuncAttributeMaxDynamicSharedMemorySize, (int)lds_consume);
    hipFuncSetAttribute((const void*)edge_scan_kernel,
                        hipFuncAttributeMaxDynamicSharedMemorySize, (int)lds_fb);

    const int rb = 256;

    if (range <= 0xFFFF && ws_size >= need_new) {
        ushort4*  entries     = (ushort4*)ws;
        float*    partial     = (float*)(ws + entries_b);
        unsigned* counts      = (unsigned*)(ws + entries_b);           // aliases partial
        unsigned* waveprefix  = counts + (size_t)NRANGE * NWAVE;
        unsigned* rangetotals = waveprefix + (size_t)NRANGE * NWAVE;   // needs 8 u32 more
        // rangetotals must survive into K4/K5 while partial is live -> put the
        // 8 totals AFTER the partial region if space allows, else at ws end.
        rangetotals = (unsigned*)(ws + ws_size - 64);

        count_kernel<<<NBLD, K1T, 0, stream>>>(ea, eb, counts, n_edges, chunk, magic);
        scan_kernel<<<1, 512, 0, stream>>>(counts, waveprefix, rangetotals);
        emit_kernel<<<NBLD, K3T, 0, stream>>>(points, force, ea, eb,
                                              waveprefix, rangetotals, entries,
                                              n_edges, chunk, range, magic);
        consume_kernel<<<NRANGE * NSLICE, K4T, lds_consume, stream>>>(
            entries, rangetotals, partial, n_points, range);
        reduce_kernel<<<(total + rb - 1) / rb, rb, 0, stream>>>(
            ext_f, partial, out, total, NSLICE);
    } else if (ws_size >= need_fb) {
        float* partial = (float*)ws;
        edge_scan_kernel<<<NRANGE * NB_FB, BLOCK, lds_fb, stream>>>(
            points, force, ea, eb, partial, out, n_edges, n_points, range, 0);
        reduce_kernel<<<(total + rb - 1) / rb, rb, 0, stream>>>(
            ext_f, partial, out, total, NB_FB);
    } else {
        hipMemcpyAsync(d_out, (const void*)ext_f, (size_t)total * sizeof(float),
                       hipMemcpyDeviceToDevice, stream);
        edge_scan_kernel<<<NRANGE * NB_FB, BLOCK, lds_fb, stream>>>(
            points, force, ea, eb, nullptr, out, n_edges, n_points, range, 1);
    }
}